// Round 18
// baseline (356.000 us; speedup 1.0000x reference)
//
#include <hip/hip_runtime.h>

#define BB 4
#define CC 64
#define NNN 4096
#define OO 64
#define KK 20
#define EPSF 1e-5f

typedef __attribute__((ext_vector_type(8))) short bf8;
typedef __attribute__((ext_vector_type(4))) float f32x4;

// ---------------- helpers ----------------
__device__ __forceinline__ short f2bf(float f) {          // RNE f32->bf16
    unsigned u = __float_as_uint(f);
    unsigned r = (u + 0x7fffu + ((u >> 16) & 1u)) >> 16;
    return (short)r;
}
__device__ __forceinline__ float bf2f(short s) {
    return __uint_as_float(((unsigned)(unsigned short)s) << 16);
}
__device__ __forceinline__ unsigned long long packkey(double d, int j) {
    unsigned long long u = __double_as_longlong(d);
    u ^= (unsigned long long)((long long)u >> 63) | 0x8000000000000000ULL;
    return (u & ~0xFFFULL) | (unsigned long long)(4095 - j);
}

// ---------------- K1: xx[n] = sum_c x[c][n]^2 in f64 ----------------
__global__ __launch_bounds__(256) void xx_kernel(const float* __restrict__ x, double* __restrict__ xx) {
    int g = blockIdx.x * 256 + threadIdx.x;          // 0..B*N-1
    int b = g >> 12, n = g & (NNN - 1);
    const float* xp = x + (size_t)b * CC * NNN + n;
    double s = 0.0;
    for (int c = 0; c < CC; ++c) {
        double v = (double)xp[(size_t)c * NNN];
        s += v * v;
    }
    xx[g] = s;
}

// ---------------- K1.5: pack x into point-major f32 + bf16 hi/lo splits ----------------
__global__ __launch_bounds__(256) void pack_kernel(const float* __restrict__ x, float* __restrict__ xT,
                                                   short* __restrict__ xbf1, short* __restrict__ xbf2) {
    __shared__ float tile[64][65];
    int tid = threadIdx.x;
    int b = blockIdx.x >> 6;                     // 64 chunks per batch
    int n0 = (blockIdx.x & 63) * 64;
    const float* xb = x + (size_t)b * CC * NNN;
    for (int i = tid; i < 64 * 16; i += 256) {   // 64 c-rows x 16 float4
        int c = i >> 4, q = i & 15;
        *(float4*)&tile[c][q * 4] = *(const float4*)(xb + (size_t)c * NNN + n0 + q * 4);
    }
    __syncthreads();
    size_t obase = ((size_t)b * NNN + n0) * 64;
    for (int i = tid; i < 64 * 64; i += 256) {
        int nl = i >> 6, c = i & 63;
        float v = tile[c][nl];
        size_t o = obase + (size_t)nl * 64 + c;
        xT[o] = v;
        short h = f2bf(v);
        xbf1[o] = h;
        xbf2[o] = f2bf(v - bf2f(h));
    }
}

// ---------------- K2: per-point projections A = x*w1a^T, Bv = x*(w1b-w1a)^T ----------------
__global__ __launch_bounds__(256) void proj_kernel(const float* __restrict__ x, const float* __restrict__ w1,
                                                   float* __restrict__ A, float* __restrict__ Bv) {
    __shared__ float xs[CC][64];       // [c][p]
    __shared__ float ws1[OO][129];     // padded
    int tid = threadIdx.x;
    int b = blockIdx.x >> 6;
    int p0 = (blockIdx.x & 63) << 6;
    const float* xb = x + (size_t)b * CC * NNN;
    for (int i = tid; i < CC * 16; i += 256) {
        int c = i >> 4, q = i & 15;
        *(float4*)&xs[c][q * 4] = *(const float4*)(xb + (size_t)c * NNN + p0 + q * 4);
    }
    for (int i = tid; i < OO * 32; i += 256) {
        int o = i >> 5, q = i & 31;
        float4 v = *(const float4*)(w1 + o * 128 + q * 4);
        ws1[o][q * 4 + 0] = v.x; ws1[o][q * 4 + 1] = v.y;
        ws1[o][q * 4 + 2] = v.z; ws1[o][q * 4 + 3] = v.w;
    }
    __syncthreads();
    int ti = tid >> 4, tj = tid & 15;
    float aA[4][4] = {{0.f}}, aD[4][4] = {{0.f}};
    for (int c = 0; c < CC; ++c) {
        float4 xv4 = *(const float4*)&xs[c][ti * 4];
        float xv[4] = {xv4.x, xv4.y, xv4.z, xv4.w};
        #pragma unroll
        for (int oo = 0; oo < 4; ++oo) {
            float wa = ws1[tj * 4 + oo][c];
            float wd = ws1[tj * 4 + oo][64 + c] - wa;
            #pragma unroll
            for (int pp = 0; pp < 4; ++pp) {
                aA[pp][oo] = fmaf(xv[pp], wa, aA[pp][oo]);
                aD[pp][oo] = fmaf(xv[pp], wd, aD[pp][oo]);
            }
        }
    }
    size_t base = ((size_t)b * NNN + p0) * 64;
    #pragma unroll
    for (int pp = 0; pp < 4; ++pp) {
        int p = ti * 4 + pp;
        *(float4*)(A  + base + (size_t)p * 64 + tj * 4) = make_float4(aA[pp][0], aA[pp][1], aA[pp][2], aA[pp][3]);
        *(float4*)(Bv + base + (size_t)p * 64 + tj * 4) = make_float4(aD[pp][0], aD[pp][1], aD[pp][2], aD[pp][3]);
    }
}

// ---------------- K3a: bf16 2-split MFMA screen -> top-32 (512 thr, 2 rows/wave) ----------------
// r17-passing structure, rebalanced: 8 waves/block; wave w computes cols w*32..+31
// (2 chains) and selects rows w*2, w*2+1. Per-wave serial insert path halves;
// waves/CU 16 -> 32. Same u32 keys, same single barrier, same math.
__global__ __launch_bounds__(512, 4) void scr_kernel(const short* __restrict__ xbf1, const short* __restrict__ xbf2,
                                                     const double* __restrict__ xx, int* __restrict__ top32) {
    __shared__ unsigned dK[2][16][260];             // 33280 B -> 4 blocks/CU (132KB)
    int tid = threadIdx.x, lane = tid & 63, w = tid >> 6;   // 8 waves
    int b = blockIdx.x >> 8, r0 = (blockIdx.x & 255) * 16;
    const short* x1b = xbf1 + (size_t)b * NNN * 64;
    const short* x2b = xbf2 + (size_t)b * NNN * 64;
    const double* xxb = xx + (size_t)b * NNN;
    int lr = lane & 15, lk = lane >> 4;
    double xr0 = xxb[r0 + 4 * lk + 0], xr1 = xxb[r0 + 4 * lk + 1],
           xr2 = xxb[r0 + 4 * lk + 2], xr3 = xxb[r0 + 4 * lk + 3];

    // A-frags: row r0+lr, k = kb*32 + lk*8 + e  (4 x short8 loads, tile-invariant)
    size_t abase = (size_t)(r0 + lr) * 64 + lk * 8;
    bf8 A1k0 = *(const bf8*)(x1b + abase);
    bf8 A2k0 = *(const bf8*)(x2b + abase);
    bf8 A1k1 = *(const bf8*)(x1b + abase + 32);
    bf8 A2k1 = *(const bf8*)(x2b + abase + 32);

    unsigned S0, S1;
    S0 = S1 = (lane < 32) ? 0u : 0xFFFFFFFFu;
    unsigned T0 = 0, T1 = 0;

    #define SELROW(RL, CUR) { \
        for (int hf = 0; hf < 4; ++hf) { \
            unsigned key = dK[CUR][w * 2 + RL][hf * 64 + lane]; \
            unsigned long long m = __ballot(key > T##RL); \
            while (m) { \
                int src = (int)__builtin_ctzll(m); m &= m - 1; \
                unsigned kb = (unsigned)__builtin_amdgcn_readlane((int)key, src); \
                if (kb > T##RL) { \
                    unsigned u = __shfl_down(S##RL, 1); \
                    unsigned mx = (S##RL < kb) ? kb : S##RL; \
                    S##RL = (u < kb) ? u : mx; \
                    T##RL = (unsigned)__builtin_amdgcn_readfirstlane((int)S##RL); \
                } \
            } \
        } \
    }
    #define SELALL(CUR) SELROW(0, CUR) SELROW(1, CUR)

    #define CHAIN(ACC, CB) { \
        size_t bb_ = (size_t)((CB) + lr) * 64 + lk * 8; \
        bf8 B1k0 = *(const bf8*)(x1b + bb_); \
        bf8 B2k0 = *(const bf8*)(x2b + bb_); \
        bf8 B1k1 = *(const bf8*)(x1b + bb_ + 32); \
        bf8 B2k1 = *(const bf8*)(x2b + bb_ + 32); \
        ACC = __builtin_amdgcn_mfma_f32_16x16x32_bf16(A1k0, B1k0, ACC, 0, 0, 0); \
        ACC = __builtin_amdgcn_mfma_f32_16x16x32_bf16(A1k1, B1k1, ACC, 0, 0, 0); \
        ACC = __builtin_amdgcn_mfma_f32_16x16x32_bf16(A1k0, B2k0, ACC, 0, 0, 0); \
        ACC = __builtin_amdgcn_mfma_f32_16x16x32_bf16(A1k1, B2k1, ACC, 0, 0, 0); \
        ACC = __builtin_amdgcn_mfma_f32_16x16x32_bf16(A2k0, B1k0, ACC, 0, 0, 0); \
        ACC = __builtin_amdgcn_mfma_f32_16x16x32_bf16(A2k1, B1k1, ACC, 0, 0, 0); \
    }

    for (int t = 0; t < 16; ++t) {
        int j0 = t * 256, cur = t & 1;
        f32x4 acc0 = {0.f, 0.f, 0.f, 0.f}, acc1 = {0.f, 0.f, 0.f, 0.f};
        CHAIN(acc0, j0 + w * 32 + 0)
        CHAIN(acc1, j0 + w * 32 + 16)
        // epilogue: u32 key = monotone-f32 dist bits[31:12] | (4095 - idx)
        #define EPI(Q, R) { \
            int col = w * 32 + (Q) * 16 + lr; \
            float df = (float)(2.0 * (double)acc##Q[R] - xr##R - xxb[j0 + col]); \
            unsigned u = __float_as_uint(df); \
            u ^= (unsigned)((int)u >> 31) | 0x80000000u; \
            dK[cur][4 * lk + R][col] = (u & 0xFFFFF000u) | (unsigned)(4095 - (j0 + col)); \
        }
        EPI(0,0) EPI(0,1) EPI(0,2) EPI(0,3)
        EPI(1,0) EPI(1,1) EPI(1,2) EPI(1,3)
        #undef EPI
        __syncthreads();               // ONE barrier: dK[cur] ready; buffer cur^1 free
        SELALL(cur);                   // select(t) overlaps other blocks' compute
    }
    #undef SELALL
    #undef SELROW
    #undef CHAIN

    if (lane < 32) {                   // unordered superset is fine
        size_t base = (size_t)b * NNN + r0 + w * 2;
        top32[(base + 0) * 32 + lane] = 4095 - (int)(S0 & 0xFFFu);
        top32[(base + 1) * 32 + lane] = 4095 - (int)(S1 & 0xFFFu);
    }
}

// ---------------- K3b: exact f64 rescore of top-32 -> sorted top-20 ----------------
__global__ __launch_bounds__(256) void resc_kernel(const float* __restrict__ xT, const double* __restrict__ xx,
                                                   const int* __restrict__ top32, int* __restrict__ idxOut) {
    int tid = threadIdx.x, lane = tid & 63, w = tid >> 6;
    int grow = blockIdx.x * 4 + w;               // global row 0..B*N-1
    int b = grow >> 12, n = grow & (NNN - 1);
    const float* xTb = xT + (size_t)b * NNN * 64;
    const double* xxb = xx + (size_t)b * NNN;
    int cand = top32[(size_t)grow * 32 + (lane & 31)];
    const float* rp = xTb + (size_t)n * 64;      // wave-uniform
    const float* cp = xTb + (size_t)cand * 64;   // per-lane contiguous
    double a0 = 0.0, a1 = 0.0, a2 = 0.0, a3 = 0.0;
    #pragma unroll
    for (int c = 0; c < CC; c += 4) {
        float4 rv = *(const float4*)(rp + c);
        float4 cv = *(const float4*)(cp + c);
        a0 = fma((double)rv.x, (double)cv.x, a0);
        a1 = fma((double)rv.y, (double)cv.y, a1);
        a2 = fma((double)rv.z, (double)cv.z, a2);
        a3 = fma((double)rv.w, (double)cv.w, a3);
    }
    double d = 2.0 * ((a0 + a1) + (a2 + a3)) - xxb[n] - xxb[cand];
    unsigned long long key = (lane < 32) ? packkey(d, cand) : 0ULL;
    unsigned long long S = (lane < KK) ? 0ULL : ~0ULL;
    unsigned long long T = 0;
    unsigned long long m = __ballot(key > T);
    while (m) {
        int src = (int)__builtin_ctzll(m); m &= m - 1;
        unsigned long long kb = __shfl(key, src);
        if (kb > T) {
            unsigned long long u = __shfl_down(S, 1);
            unsigned long long mx = (S < kb) ? kb : S;
            S = (u < kb) ? u : mx;
            T = __shfl(S, 0);
        }
    }
    if (lane < KK)                              // ascending lanes -> descending out
        idxOut[(size_t)grow * KK + (KK - 1 - lane)] = 4095 - (int)(S & 0xFFFULL);
}

// ---------------- K4: 16 points/block (4/CU), h1/h2/max fused ----------------
__global__ __launch_bounds__(256) void edge_kernel(const float* __restrict__ A, const float* __restrict__ Bv,
        const int* __restrict__ idx, const float* __restrict__ w2,
        const float* __restrict__ g1, const float* __restrict__ be1, const float* __restrict__ m1, const float* __restrict__ v1,
        const float* __restrict__ g2, const float* __restrict__ be2, const float* __restrict__ m2, const float* __restrict__ v2,
        float* __restrict__ out) {
    __shared__ float h1buf[4][KK][64];
    __shared__ float resT[64][17];
    int tid = threadIdx.x;
    int lane = tid & 63, w = tid >> 6;
    int b = blockIdx.x >> 8;
    int n0 = (blockIdx.x & 255) * 16;
    float s1 = g1[lane] * rsqrtf(v1[lane] + EPSF);
    float bb1 = be1[lane] - m1[lane] * s1;
    float s2 = g2[lane] * rsqrtf(v2[lane] + EPSF);
    float bb2 = be2[lane] - m2[lane] * s2;
    float w2r[64];
    #pragma unroll
    for (int o = 0; o < 64; ++o) w2r[o] = w2[lane * 64 + o];
    for (int p = 0; p < 4; ++p) {
        int n = n0 + w * 4 + p;
        size_t pb = (size_t)b * NNN + n;
        float bv = Bv[pb * 64 + lane];
        const int* ip = idx + pb * KK;
        #pragma unroll
        for (int k = 0; k < KK; ++k) {
            int nb = ip[k];
            float av = A[((size_t)b * NNN + nb) * 64 + lane];
            h1buf[w][k][lane] = fmaxf(0.f, fmaf(av + bv, s1, bb1));
        }
        __syncthreads();
        float mx = -1e30f;
        for (int k = 0; k < KK; ++k) {
            const float4* hb = (const float4*)&h1buf[w][k][0];
            float dot = 0.f;
            #pragma unroll
            for (int o4 = 0; o4 < 16; ++o4) {
                float4 h = hb[o4];
                dot = fmaf(w2r[o4 * 4 + 0], h.x, dot);
                dot = fmaf(w2r[o4 * 4 + 1], h.y, dot);
                dot = fmaf(w2r[o4 * 4 + 2], h.z, dot);
                dot = fmaf(w2r[o4 * 4 + 3], h.w, dot);
            }
            mx = fmaxf(mx, fmaxf(0.f, fmaf(dot, s2, bb2)));
        }
        resT[lane][w * 4 + p] = mx;
        __syncthreads();
    }
    for (int i = tid; i < 64 * 16; i += 256) {
        int o2 = i >> 4, pp = i & 15;
        out[((size_t)b * 64 + o2) * NNN + n0 + pp] = resT[o2][pp];
    }
}

extern "C" void kernel_launch(void* const* d_in, const int* in_sizes, int n_in,
                              void* d_out, int out_size, void* d_ws, size_t ws_size,
                              hipStream_t stream) {
    const float* x   = (const float*)d_in[0];
    const float* w1  = (const float*)d_in[1];
    const float* g1  = (const float*)d_in[2];
    const float* be1 = (const float*)d_in[3];
    const float* m1  = (const float*)d_in[4];
    const float* v1  = (const float*)d_in[5];
    const float* w2  = (const float*)d_in[6];
    const float* g2  = (const float*)d_in[7];
    const float* be2 = (const float*)d_in[8];
    const float* m2  = (const float*)d_in[9];
    const float* v2  = (const float*)d_in[10];
    // ws: xx 128KB | A 4MB | Bv 4MB | idx20 1.31MB | top32 2MB | xT 4MB | xbf1 2MB | xbf2 2MB
    char* ws = (char*)d_ws;
    double* xx   = (double*)ws;
    float*  A    = (float*)(ws + 131072);
    float*  Bv   = (float*)(ws + 131072 + 4194304);
    int*    nidx = (int*)(ws + 131072 + 2 * 4194304);
    int*    t32  = (int*)(ws + 131072 + 2 * 4194304 + 1310720);
    float*  xT   = (float*)(ws + 131072 + 2 * 4194304 + 1310720 + 2097152);
    short*  xbf1 = (short*)(ws + 131072 + 3 * 4194304 + 1310720 + 2097152);
    short*  xbf2 = (short*)(ws + 131072 + 3 * 4194304 + 1310720 + 2 * 2097152);
    float*  out  = (float*)d_out;

    hipLaunchKernelGGL(xx_kernel,   dim3(BB * NNN / 256), dim3(256), 0, stream, x, xx);
    hipLaunchKernelGGL(pack_kernel, dim3(BB * 64), dim3(256), 0, stream, x, xT, xbf1, xbf2);
    hipLaunchKernelGGL(proj_kernel, dim3(BB * (NNN / 64)), dim3(256), 0, stream, x, w1, A, Bv);
    hipLaunchKernelGGL(scr_kernel,  dim3(BB * (NNN / 16)), dim3(512), 0, stream, xbf1, xbf2, xx, t32);
    hipLaunchKernelGGL(resc_kernel, dim3(BB * NNN / 4), dim3(256), 0, stream, xT, xx, t32, nidx);
    hipLaunchKernelGGL(edge_kernel, dim3(BB * (NNN / 16)), dim3(256), 0, stream,
                       A, Bv, nidx, w2, g1, be1, m1, v1, g2, be2, m2, v2, out);
}

// Round 19
// 347.470 us; speedup vs baseline: 1.0245x; 1.0245x over previous
//
#include <hip/hip_runtime.h>

#define BB 4
#define CC 64
#define NNN 4096
#define OO 64
#define KK 20
#define EPSF 1e-5f

typedef __attribute__((ext_vector_type(8))) short bf8;
typedef __attribute__((ext_vector_type(4))) float f32x4;

// ---------------- helpers ----------------
__device__ __forceinline__ short f2bf(float f) {          // RNE f32->bf16
    unsigned u = __float_as_uint(f);
    unsigned r = (u + 0x7fffu + ((u >> 16) & 1u)) >> 16;
    return (short)r;
}
__device__ __forceinline__ float bf2f(short s) {
    return __uint_as_float(((unsigned)(unsigned short)s) << 16);
}
__device__ __forceinline__ unsigned long long packkey(double d, int j) {
    unsigned long long u = __double_as_longlong(d);
    u ^= (unsigned long long)((long long)u >> 63) | 0x8000000000000000ULL;
    return (u & ~0xFFFULL) | (unsigned long long)(4095 - j);
}

// ---------------- K1: xx[n] = sum_c x[c][n]^2 in f64 ----------------
__global__ __launch_bounds__(256) void xx_kernel(const float* __restrict__ x, double* __restrict__ xx) {
    int g = blockIdx.x * 256 + threadIdx.x;          // 0..B*N-1
    int b = g >> 12, n = g & (NNN - 1);
    const float* xp = x + (size_t)b * CC * NNN + n;
    double s = 0.0;
    for (int c = 0; c < CC; ++c) {
        double v = (double)xp[(size_t)c * NNN];
        s += v * v;
    }
    xx[g] = s;
}

// ---------------- K1.5: pack x into point-major f32 + bf16 hi/lo splits ----------------
__global__ __launch_bounds__(256) void pack_kernel(const float* __restrict__ x, float* __restrict__ xT,
                                                   short* __restrict__ xbf1, short* __restrict__ xbf2) {
    __shared__ float tile[64][65];
    int tid = threadIdx.x;
    int b = blockIdx.x >> 6;                     // 64 chunks per batch
    int n0 = (blockIdx.x & 63) * 64;
    const float* xb = x + (size_t)b * CC * NNN;
    for (int i = tid; i < 64 * 16; i += 256) {   // 64 c-rows x 16 float4
        int c = i >> 4, q = i & 15;
        *(float4*)&tile[c][q * 4] = *(const float4*)(xb + (size_t)c * NNN + n0 + q * 4);
    }
    __syncthreads();
    size_t obase = ((size_t)b * NNN + n0) * 64;
    for (int i = tid; i < 64 * 64; i += 256) {
        int nl = i >> 6, c = i & 63;
        float v = tile[c][nl];
        size_t o = obase + (size_t)nl * 64 + c;
        xT[o] = v;
        short h = f2bf(v);
        xbf1[o] = h;
        xbf2[o] = f2bf(v - bf2f(h));
    }
}

// ---------------- K2: per-point projections A = x*w1a^T, Bv = x*(w1b-w1a)^T ----------------
__global__ __launch_bounds__(256) void proj_kernel(const float* __restrict__ x, const float* __restrict__ w1,
                                                   float* __restrict__ A, float* __restrict__ Bv) {
    __shared__ float xs[CC][64];       // [c][p]
    __shared__ float ws1[OO][129];     // padded
    int tid = threadIdx.x;
    int b = blockIdx.x >> 6;
    int p0 = (blockIdx.x & 63) << 6;
    const float* xb = x + (size_t)b * CC * NNN;
    for (int i = tid; i < CC * 16; i += 256) {
        int c = i >> 4, q = i & 15;
        *(float4*)&xs[c][q * 4] = *(const float4*)(xb + (size_t)c * NNN + p0 + q * 4);
    }
    for (int i = tid; i < OO * 32; i += 256) {
        int o = i >> 5, q = i & 31;
        float4 v = *(const float4*)(w1 + o * 128 + q * 4);
        ws1[o][q * 4 + 0] = v.x; ws1[o][q * 4 + 1] = v.y;
        ws1[o][q * 4 + 2] = v.z; ws1[o][q * 4 + 3] = v.w;
    }
    __syncthreads();
    int ti = tid >> 4, tj = tid & 15;
    float aA[4][4] = {{0.f}}, aD[4][4] = {{0.f}};
    for (int c = 0; c < CC; ++c) {
        float4 xv4 = *(const float4*)&xs[c][ti * 4];
        float xv[4] = {xv4.x, xv4.y, xv4.z, xv4.w};
        #pragma unroll
        for (int oo = 0; oo < 4; ++oo) {
            float wa = ws1[tj * 4 + oo][c];
            float wd = ws1[tj * 4 + oo][64 + c] - wa;
            #pragma unroll
            for (int pp = 0; pp < 4; ++pp) {
                aA[pp][oo] = fmaf(xv[pp], wa, aA[pp][oo]);
                aD[pp][oo] = fmaf(xv[pp], wd, aD[pp][oo]);
            }
        }
    }
    size_t base = ((size_t)b * NNN + p0) * 64;
    #pragma unroll
    for (int pp = 0; pp < 4; ++pp) {
        int p = ti * 4 + pp;
        *(float4*)(A  + base + (size_t)p * 64 + tj * 4) = make_float4(aA[pp][0], aA[pp][1], aA[pp][2], aA[pp][3]);
        *(float4*)(Bv + base + (size_t)p * 64 + tj * 4) = make_float4(aD[pp][0], aD[pp][1], aD[pp][2], aD[pp][3]);
    }
}

// ---------------- K3a: bf16 2-split MFMA screen -> top-32 (r17 geometry + hoisted reads) ----------------
// 256 thr / 4 waves (best measured config). Wave w: cols w*64..+63 (4 chains),
// selects rows w*4..+3. u32 keys, single barrier/tile, double-buffered dK.
// New: all 4 hf key-reads issue back-to-back (pipelined lgkmcnt) before processing.
__global__ __launch_bounds__(256, 4) void scr_kernel(const short* __restrict__ xbf1, const short* __restrict__ xbf2,
                                                     const double* __restrict__ xx, int* __restrict__ top32) {
    __shared__ unsigned dK[2][16][260];             // 33280 B -> 4 blocks/CU
    int tid = threadIdx.x, lane = tid & 63, w = tid >> 6;   // 4 waves
    int b = blockIdx.x >> 8, r0 = (blockIdx.x & 255) * 16;
    const short* x1b = xbf1 + (size_t)b * NNN * 64;
    const short* x2b = xbf2 + (size_t)b * NNN * 64;
    const double* xxb = xx + (size_t)b * NNN;
    int lr = lane & 15, lk = lane >> 4;
    double xr0 = xxb[r0 + 4 * lk + 0], xr1 = xxb[r0 + 4 * lk + 1],
           xr2 = xxb[r0 + 4 * lk + 2], xr3 = xxb[r0 + 4 * lk + 3];

    // A-frags: row r0+lr, k = kb*32 + lk*8 + e  (4 x short8 loads, tile-invariant)
    size_t abase = (size_t)(r0 + lr) * 64 + lk * 8;
    bf8 A1k0 = *(const bf8*)(x1b + abase);
    bf8 A2k0 = *(const bf8*)(x2b + abase);
    bf8 A1k1 = *(const bf8*)(x1b + abase + 32);
    bf8 A2k1 = *(const bf8*)(x2b + abase + 32);

    unsigned S0, S1, S2, S3;
    S0 = S1 = S2 = S3 = (lane < 32) ? 0u : 0xFFFFFFFFu;
    unsigned T0 = 0, T1 = 0, T2 = 0, T3 = 0;

    #define PROC(RL, KEY) { \
        unsigned long long m = __ballot((KEY) > T##RL); \
        while (m) { \
            int src = (int)__builtin_ctzll(m); m &= m - 1; \
            unsigned kb = (unsigned)__builtin_amdgcn_readlane((int)(KEY), src); \
            if (kb > T##RL) { \
                unsigned u = __shfl_down(S##RL, 1); \
                unsigned mx = (S##RL < kb) ? kb : S##RL; \
                S##RL = (u < kb) ? u : mx; \
                T##RL = (unsigned)__builtin_amdgcn_readfirstlane((int)S##RL); \
            } \
        } \
    }
    #define SELROW(RL, CUR) { \
        unsigned k0_ = dK[CUR][w * 4 + RL][0 * 64 + lane]; \
        unsigned k1_ = dK[CUR][w * 4 + RL][1 * 64 + lane]; \
        unsigned k2_ = dK[CUR][w * 4 + RL][2 * 64 + lane]; \
        unsigned k3_ = dK[CUR][w * 4 + RL][3 * 64 + lane]; \
        PROC(RL, k0_) PROC(RL, k1_) PROC(RL, k2_) PROC(RL, k3_) \
    }
    #define SELALL(CUR) SELROW(0, CUR) SELROW(1, CUR) SELROW(2, CUR) SELROW(3, CUR)

    #define CHAIN(ACC, CB) { \
        size_t bb_ = (size_t)((CB) + lr) * 64 + lk * 8; \
        bf8 B1k0 = *(const bf8*)(x1b + bb_); \
        bf8 B2k0 = *(const bf8*)(x2b + bb_); \
        bf8 B1k1 = *(const bf8*)(x1b + bb_ + 32); \
        bf8 B2k1 = *(const bf8*)(x2b + bb_ + 32); \
        ACC = __builtin_amdgcn_mfma_f32_16x16x32_bf16(A1k0, B1k0, ACC, 0, 0, 0); \
        ACC = __builtin_amdgcn_mfma_f32_16x16x32_bf16(A1k1, B1k1, ACC, 0, 0, 0); \
        ACC = __builtin_amdgcn_mfma_f32_16x16x32_bf16(A1k0, B2k0, ACC, 0, 0, 0); \
        ACC = __builtin_amdgcn_mfma_f32_16x16x32_bf16(A1k1, B2k1, ACC, 0, 0, 0); \
        ACC = __builtin_amdgcn_mfma_f32_16x16x32_bf16(A2k0, B1k0, ACC, 0, 0, 0); \
        ACC = __builtin_amdgcn_mfma_f32_16x16x32_bf16(A2k1, B1k1, ACC, 0, 0, 0); \
    }

    for (int t = 0; t < 16; ++t) {
        int j0 = t * 256, cur = t & 1;
        f32x4 acc0 = {0.f, 0.f, 0.f, 0.f}, acc1 = {0.f, 0.f, 0.f, 0.f};
        f32x4 acc2 = {0.f, 0.f, 0.f, 0.f}, acc3 = {0.f, 0.f, 0.f, 0.f};
        CHAIN(acc0, j0 + w * 64 + 0)
        CHAIN(acc1, j0 + w * 64 + 16)
        CHAIN(acc2, j0 + w * 64 + 32)
        CHAIN(acc3, j0 + w * 64 + 48)
        // epilogue: u32 key = monotone-f32 dist bits[31:12] | (4095 - idx)
        #define EPI(Q, R) { \
            int col = w * 64 + (Q) * 16 + lr; \
            float df = (float)(2.0 * (double)acc##Q[R] - xr##R - xxb[j0 + col]); \
            unsigned u = __float_as_uint(df); \
            u ^= (unsigned)((int)u >> 31) | 0x80000000u; \
            dK[cur][4 * lk + R][col] = (u & 0xFFFFF000u) | (unsigned)(4095 - (j0 + col)); \
        }
        EPI(0,0) EPI(0,1) EPI(0,2) EPI(0,3)
        EPI(1,0) EPI(1,1) EPI(1,2) EPI(1,3)
        EPI(2,0) EPI(2,1) EPI(2,2) EPI(2,3)
        EPI(3,0) EPI(3,1) EPI(3,2) EPI(3,3)
        #undef EPI
        __syncthreads();               // ONE barrier: dK[cur] ready; buffer cur^1 free
        SELALL(cur);                   // select(t) overlaps other blocks' compute
    }
    #undef SELALL
    #undef SELROW
    #undef PROC
    #undef CHAIN

    if (lane < 32) {                   // unordered superset is fine
        size_t base = (size_t)b * NNN + r0 + w * 4;
        top32[(base + 0) * 32 + lane] = 4095 - (int)(S0 & 0xFFFu);
        top32[(base + 1) * 32 + lane] = 4095 - (int)(S1 & 0xFFFu);
        top32[(base + 2) * 32 + lane] = 4095 - (int)(S2 & 0xFFFu);
        top32[(base + 3) * 32 + lane] = 4095 - (int)(S3 & 0xFFFu);
    }
}

// ---------------- K3b: exact f64 rescore of top-32 -> sorted top-20 ----------------
__global__ __launch_bounds__(256) void resc_kernel(const float* __restrict__ xT, const double* __restrict__ xx,
                                                   const int* __restrict__ top32, int* __restrict__ idxOut) {
    int tid = threadIdx.x, lane = tid & 63, w = tid >> 6;
    int grow = blockIdx.x * 4 + w;               // global row 0..B*N-1
    int b = grow >> 12, n = grow & (NNN - 1);
    const float* xTb = xT + (size_t)b * NNN * 64;
    const double* xxb = xx + (size_t)b * NNN;
    int cand = top32[(size_t)grow * 32 + (lane & 31)];
    const float* rp = xTb + (size_t)n * 64;      // wave-uniform
    const float* cp = xTb + (size_t)cand * 64;   // per-lane contiguous
    double a0 = 0.0, a1 = 0.0, a2 = 0.0, a3 = 0.0;
    #pragma unroll
    for (int c = 0; c < CC; c += 4) {
        float4 rv = *(const float4*)(rp + c);
        float4 cv = *(const float4*)(cp + c);
        a0 = fma((double)rv.x, (double)cv.x, a0);
        a1 = fma((double)rv.y, (double)cv.y, a1);
        a2 = fma((double)rv.z, (double)cv.z, a2);
        a3 = fma((double)rv.w, (double)cv.w, a3);
    }
    double d = 2.0 * ((a0 + a1) + (a2 + a3)) - xxb[n] - xxb[cand];
    unsigned long long key = (lane < 32) ? packkey(d, cand) : 0ULL;
    unsigned long long S = (lane < KK) ? 0ULL : ~0ULL;
    unsigned long long T = 0;
    unsigned long long m = __ballot(key > T);
    while (m) {
        int src = (int)__builtin_ctzll(m); m &= m - 1;
        unsigned long long kb = __shfl(key, src);
        if (kb > T) {
            unsigned long long u = __shfl_down(S, 1);
            unsigned long long mx = (S < kb) ? kb : S;
            S = (u < kb) ? u : mx;
            T = __shfl(S, 0);
        }
    }
    if (lane < KK)                              // ascending lanes -> descending out
        idxOut[(size_t)grow * KK + (KK - 1 - lane)] = 4095 - (int)(S & 0xFFFULL);
}

// ---------------- K4: 16 points/block (4/CU), h1/h2/max fused ----------------
__global__ __launch_bounds__(256) void edge_kernel(const float* __restrict__ A, const float* __restrict__ Bv,
        const int* __restrict__ idx, const float* __restrict__ w2,
        const float* __restrict__ g1, const float* __restrict__ be1, const float* __restrict__ m1, const float* __restrict__ v1,
        const float* __restrict__ g2, const float* __restrict__ be2, const float* __restrict__ m2, const float* __restrict__ v2,
        float* __restrict__ out) {
    __shared__ float h1buf[4][KK][64];
    __shared__ float resT[64][17];
    int tid = threadIdx.x;
    int lane = tid & 63, w = tid >> 6;
    int b = blockIdx.x >> 8;
    int n0 = (blockIdx.x & 255) * 16;
    float s1 = g1[lane] * rsqrtf(v1[lane] + EPSF);
    float bb1 = be1[lane] - m1[lane] * s1;
    float s2 = g2[lane] * rsqrtf(v2[lane] + EPSF);
    float bb2 = be2[lane] - m2[lane] * s2;
    float w2r[64];
    #pragma unroll
    for (int o = 0; o < 64; ++o) w2r[o] = w2[lane * 64 + o];
    for (int p = 0; p < 4; ++p) {
        int n = n0 + w * 4 + p;
        size_t pb = (size_t)b * NNN + n;
        float bv = Bv[pb * 64 + lane];
        const int* ip = idx + pb * KK;
        #pragma unroll
        for (int k = 0; k < KK; ++k) {
            int nb = ip[k];
            float av = A[((size_t)b * NNN + nb) * 64 + lane];
            h1buf[w][k][lane] = fmaxf(0.f, fmaf(av + bv, s1, bb1));
        }
        __syncthreads();
        float mx = -1e30f;
        for (int k = 0; k < KK; ++k) {
            const float4* hb = (const float4*)&h1buf[w][k][0];
            float dot = 0.f;
            #pragma unroll
            for (int o4 = 0; o4 < 16; ++o4) {
                float4 h = hb[o4];
                dot = fmaf(w2r[o4 * 4 + 0], h.x, dot);
                dot = fmaf(w2r[o4 * 4 + 1], h.y, dot);
                dot = fmaf(w2r[o4 * 4 + 2], h.z, dot);
                dot = fmaf(w2r[o4 * 4 + 3], h.w, dot);
            }
            mx = fmaxf(mx, fmaxf(0.f, fmaf(dot, s2, bb2)));
        }
        resT[lane][w * 4 + p] = mx;
        __syncthreads();
    }
    for (int i = tid; i < 64 * 16; i += 256) {
        int o2 = i >> 4, pp = i & 15;
        out[((size_t)b * 64 + o2) * NNN + n0 + pp] = resT[o2][pp];
    }
}

extern "C" void kernel_launch(void* const* d_in, const int* in_sizes, int n_in,
                              void* d_out, int out_size, void* d_ws, size_t ws_size,
                              hipStream_t stream) {
    const float* x   = (const float*)d_in[0];
    const float* w1  = (const float*)d_in[1];
    const float* g1  = (const float*)d_in[2];
    const float* be1 = (const float*)d_in[3];
    const float* m1  = (const float*)d_in[4];
    const float* v1  = (const float*)d_in[5];
    const float* w2  = (const float*)d_in[6];
    const float* g2  = (const float*)d_in[7];
    const float* be2 = (const float*)d_in[8];
    const float* m2  = (const float*)d_in[9];
    const float* v2  = (const float*)d_in[10];
    // ws: xx 128KB | A 4MB | Bv 4MB | idx20 1.31MB | top32 2MB | xT 4MB | xbf1 2MB | xbf2 2MB
    char* ws = (char*)d_ws;
    double* xx   = (double*)ws;
    float*  A    = (float*)(ws + 131072);
    float*  Bv   = (float*)(ws + 131072 + 4194304);
    int*    nidx = (int*)(ws + 131072 + 2 * 4194304);
    int*    t32  = (int*)(ws + 131072 + 2 * 4194304 + 1310720);
    float*  xT   = (float*)(ws + 131072 + 2 * 4194304 + 1310720 + 2097152);
    short*  xbf1 = (short*)(ws + 131072 + 3 * 4194304 + 1310720 + 2097152);
    short*  xbf2 = (short*)(ws + 131072 + 3 * 4194304 + 1310720 + 2 * 2097152);
    float*  out  = (float*)d_out;

    hipLaunchKernelGGL(xx_kernel,   dim3(BB * NNN / 256), dim3(256), 0, stream, x, xx);
    hipLaunchKernelGGL(pack_kernel, dim3(BB * 64), dim3(256), 0, stream, x, xT, xbf1, xbf2);
    hipLaunchKernelGGL(proj_kernel, dim3(BB * (NNN / 64)), dim3(256), 0, stream, x, w1, A, Bv);
    hipLaunchKernelGGL(scr_kernel,  dim3(BB * (NNN / 16)), dim3(256), 0, stream, xbf1, xbf2, xx, t32);
    hipLaunchKernelGGL(resc_kernel, dim3(BB * NNN / 4), dim3(256), 0, stream, xT, xx, t32, nidx);
    hipLaunchKernelGGL(edge_kernel, dim3(BB * (NNN / 16)), dim3(256), 0, stream,
                       A, Bv, nidx, w2, g1, be1, m1, v1, g2, be2, m2, v2, out);
}

// Round 20
// 330.467 us; speedup vs baseline: 1.0773x; 1.0515x over previous
//
#include <hip/hip_runtime.h>

#define BB 4
#define CC 64
#define NNN 4096
#define OO 64
#define KK 20
#define EPSF 1e-5f

typedef __attribute__((ext_vector_type(8))) short bf8;
typedef __attribute__((ext_vector_type(4))) float f32x4;

// ---------------- helpers ----------------
__device__ __forceinline__ short f2bf(float f) {          // RNE f32->bf16
    unsigned u = __float_as_uint(f);
    unsigned r = (u + 0x7fffu + ((u >> 16) & 1u)) >> 16;
    return (short)r;
}
__device__ __forceinline__ float bf2f(short s) {
    return __uint_as_float(((unsigned)(unsigned short)s) << 16);
}
__device__ __forceinline__ unsigned long long packkey(double d, int j) {
    unsigned long long u = __double_as_longlong(d);
    u ^= (unsigned long long)((long long)u >> 63) | 0x8000000000000000ULL;
    return (u & ~0xFFFULL) | (unsigned long long)(4095 - j);
}

// ---------------- K1: pack x into point-major f32 + bf16 hi/lo splits, fused xx ----------------
// 256 blocks; block = one (b, 64-point chunk). LDS transpose, coalesced in+out.
// xx fused: threads 0..63 sum tile[c][n]^2 in f64 ASCENDING c -- bit-identical
// to the r1-validated xx_kernel (same f32 inputs, same summation order).
__global__ __launch_bounds__(256) void pack_kernel(const float* __restrict__ x, float* __restrict__ xT,
                                                   short* __restrict__ xbf1, short* __restrict__ xbf2,
                                                   double* __restrict__ xx) {
    __shared__ float tile[64][65];
    int tid = threadIdx.x;
    int b = blockIdx.x >> 6;                     // 64 chunks per batch
    int n0 = (blockIdx.x & 63) * 64;
    const float* xb = x + (size_t)b * CC * NNN;
    for (int i = tid; i < 64 * 16; i += 256) {   // 64 c-rows x 16 float4
        int c = i >> 4, q = i & 15;
        *(float4*)&tile[c][q * 4] = *(const float4*)(xb + (size_t)c * NNN + n0 + q * 4);
    }
    __syncthreads();
    if (tid < 64) {                              // fused xx (ascending c, f64)
        double s = 0.0;
        for (int c = 0; c < CC; ++c) {
            double v = (double)tile[c][tid];
            s += v * v;
        }
        xx[(size_t)b * NNN + n0 + tid] = s;
    }
    size_t obase = ((size_t)b * NNN + n0) * 64;
    for (int i = tid; i < 64 * 64; i += 256) {
        int nl = i >> 6, c = i & 63;
        float v = tile[c][nl];
        size_t o = obase + (size_t)nl * 64 + c;
        xT[o] = v;
        short h = f2bf(v);
        xbf1[o] = h;
        xbf2[o] = f2bf(v - bf2f(h));
    }
}

// ---------------- K2: per-point projections A = x*w1a^T, Bv = x*(w1b-w1a)^T ----------------
__global__ __launch_bounds__(256) void proj_kernel(const float* __restrict__ x, const float* __restrict__ w1,
                                                   float* __restrict__ A, float* __restrict__ Bv) {
    __shared__ float xs[CC][64];       // [c][p]
    __shared__ float ws1[OO][129];     // padded
    int tid = threadIdx.x;
    int b = blockIdx.x >> 6;
    int p0 = (blockIdx.x & 63) << 6;
    const float* xb = x + (size_t)b * CC * NNN;
    for (int i = tid; i < CC * 16; i += 256) {
        int c = i >> 4, q = i & 15;
        *(float4*)&xs[c][q * 4] = *(const float4*)(xb + (size_t)c * NNN + p0 + q * 4);
    }
    for (int i = tid; i < OO * 32; i += 256) {
        int o = i >> 5, q = i & 31;
        float4 v = *(const float4*)(w1 + o * 128 + q * 4);
        ws1[o][q * 4 + 0] = v.x; ws1[o][q * 4 + 1] = v.y;
        ws1[o][q * 4 + 2] = v.z; ws1[o][q * 4 + 3] = v.w;
    }
    __syncthreads();
    int ti = tid >> 4, tj = tid & 15;
    float aA[4][4] = {{0.f}}, aD[4][4] = {{0.f}};
    for (int c = 0; c < CC; ++c) {
        float4 xv4 = *(const float4*)&xs[c][ti * 4];
        float xv[4] = {xv4.x, xv4.y, xv4.z, xv4.w};
        #pragma unroll
        for (int oo = 0; oo < 4; ++oo) {
            float wa = ws1[tj * 4 + oo][c];
            float wd = ws1[tj * 4 + oo][64 + c] - wa;
            #pragma unroll
            for (int pp = 0; pp < 4; ++pp) {
                aA[pp][oo] = fmaf(xv[pp], wa, aA[pp][oo]);
                aD[pp][oo] = fmaf(xv[pp], wd, aD[pp][oo]);
            }
        }
    }
    size_t base = ((size_t)b * NNN + p0) * 64;
    #pragma unroll
    for (int pp = 0; pp < 4; ++pp) {
        int p = ti * 4 + pp;
        *(float4*)(A  + base + (size_t)p * 64 + tj * 4) = make_float4(aA[pp][0], aA[pp][1], aA[pp][2], aA[pp][3]);
        *(float4*)(Bv + base + (size_t)p * 64 + tj * 4) = make_float4(aD[pp][0], aD[pp][1], aD[pp][2], aD[pp][3]);
    }
}

// ---------------- K3a: bf16 2-split MFMA screen -> top-32 (r19 geometry, UNCHANGED) ----------------
__global__ __launch_bounds__(256, 4) void scr_kernel(const short* __restrict__ xbf1, const short* __restrict__ xbf2,
                                                     const double* __restrict__ xx, int* __restrict__ top32) {
    __shared__ unsigned dK[2][16][260];             // 33280 B -> 4 blocks/CU
    int tid = threadIdx.x, lane = tid & 63, w = tid >> 6;   // 4 waves
    int b = blockIdx.x >> 8, r0 = (blockIdx.x & 255) * 16;
    const short* x1b = xbf1 + (size_t)b * NNN * 64;
    const short* x2b = xbf2 + (size_t)b * NNN * 64;
    const double* xxb = xx + (size_t)b * NNN;
    int lr = lane & 15, lk = lane >> 4;
    double xr0 = xxb[r0 + 4 * lk + 0], xr1 = xxb[r0 + 4 * lk + 1],
           xr2 = xxb[r0 + 4 * lk + 2], xr3 = xxb[r0 + 4 * lk + 3];

    size_t abase = (size_t)(r0 + lr) * 64 + lk * 8;
    bf8 A1k0 = *(const bf8*)(x1b + abase);
    bf8 A2k0 = *(const bf8*)(x2b + abase);
    bf8 A1k1 = *(const bf8*)(x1b + abase + 32);
    bf8 A2k1 = *(const bf8*)(x2b + abase + 32);

    unsigned S0, S1, S2, S3;
    S0 = S1 = S2 = S3 = (lane < 32) ? 0u : 0xFFFFFFFFu;
    unsigned T0 = 0, T1 = 0, T2 = 0, T3 = 0;

    #define PROC(RL, KEY) { \
        unsigned long long m = __ballot((KEY) > T##RL); \
        while (m) { \
            int src = (int)__builtin_ctzll(m); m &= m - 1; \
            unsigned kb = (unsigned)__builtin_amdgcn_readlane((int)(KEY), src); \
            if (kb > T##RL) { \
                unsigned u = __shfl_down(S##RL, 1); \
                unsigned mx = (S##RL < kb) ? kb : S##RL; \
                S##RL = (u < kb) ? u : mx; \
                T##RL = (unsigned)__builtin_amdgcn_readfirstlane((int)S##RL); \
            } \
        } \
    }
    #define SELROW(RL, CUR) { \
        unsigned k0_ = dK[CUR][w * 4 + RL][0 * 64 + lane]; \
        unsigned k1_ = dK[CUR][w * 4 + RL][1 * 64 + lane]; \
        unsigned k2_ = dK[CUR][w * 4 + RL][2 * 64 + lane]; \
        unsigned k3_ = dK[CUR][w * 4 + RL][3 * 64 + lane]; \
        PROC(RL, k0_) PROC(RL, k1_) PROC(RL, k2_) PROC(RL, k3_) \
    }
    #define SELALL(CUR) SELROW(0, CUR) SELROW(1, CUR) SELROW(2, CUR) SELROW(3, CUR)

    #define CHAIN(ACC, CB) { \
        size_t bb_ = (size_t)((CB) + lr) * 64 + lk * 8; \
        bf8 B1k0 = *(const bf8*)(x1b + bb_); \
        bf8 B2k0 = *(const bf8*)(x2b + bb_); \
        bf8 B1k1 = *(const bf8*)(x1b + bb_ + 32); \
        bf8 B2k1 = *(const bf8*)(x2b + bb_ + 32); \
        ACC = __builtin_amdgcn_mfma_f32_16x16x32_bf16(A1k0, B1k0, ACC, 0, 0, 0); \
        ACC = __builtin_amdgcn_mfma_f32_16x16x32_bf16(A1k1, B1k1, ACC, 0, 0, 0); \
        ACC = __builtin_amdgcn_mfma_f32_16x16x32_bf16(A1k0, B2k0, ACC, 0, 0, 0); \
        ACC = __builtin_amdgcn_mfma_f32_16x16x32_bf16(A1k1, B2k1, ACC, 0, 0, 0); \
        ACC = __builtin_amdgcn_mfma_f32_16x16x32_bf16(A2k0, B1k0, ACC, 0, 0, 0); \
        ACC = __builtin_amdgcn_mfma_f32_16x16x32_bf16(A2k1, B1k1, ACC, 0, 0, 0); \
    }

    for (int t = 0; t < 16; ++t) {
        int j0 = t * 256, cur = t & 1;
        f32x4 acc0 = {0.f, 0.f, 0.f, 0.f}, acc1 = {0.f, 0.f, 0.f, 0.f};
        f32x4 acc2 = {0.f, 0.f, 0.f, 0.f}, acc3 = {0.f, 0.f, 0.f, 0.f};
        CHAIN(acc0, j0 + w * 64 + 0)
        CHAIN(acc1, j0 + w * 64 + 16)
        CHAIN(acc2, j0 + w * 64 + 32)
        CHAIN(acc3, j0 + w * 64 + 48)
        #define EPI(Q, R) { \
            int col = w * 64 + (Q) * 16 + lr; \
            float df = (float)(2.0 * (double)acc##Q[R] - xr##R - xxb[j0 + col]); \
            unsigned u = __float_as_uint(df); \
            u ^= (unsigned)((int)u >> 31) | 0x80000000u; \
            dK[cur][4 * lk + R][col] = (u & 0xFFFFF000u) | (unsigned)(4095 - (j0 + col)); \
        }
        EPI(0,0) EPI(0,1) EPI(0,2) EPI(0,3)
        EPI(1,0) EPI(1,1) EPI(1,2) EPI(1,3)
        EPI(2,0) EPI(2,1) EPI(2,2) EPI(2,3)
        EPI(3,0) EPI(3,1) EPI(3,2) EPI(3,3)
        #undef EPI
        __syncthreads();               // ONE barrier: dK[cur] ready; buffer cur^1 free
        SELALL(cur);
    }
    #undef SELALL
    #undef SELROW
    #undef PROC
    #undef CHAIN

    if (lane < 32) {
        size_t base = (size_t)b * NNN + r0 + w * 4;
        top32[(base + 0) * 32 + lane] = 4095 - (int)(S0 & 0xFFFu);
        top32[(base + 1) * 32 + lane] = 4095 - (int)(S1 & 0xFFFu);
        top32[(base + 2) * 32 + lane] = 4095 - (int)(S2 & 0xFFFu);
        top32[(base + 3) * 32 + lane] = 4095 - (int)(S3 & 0xFFFu);
    }
}

// ---------------- K3b: exact f64 rescore, split-c across lane halves ----------------
// Lane j and j+32 share candidate (lane&31): j sums c=0..31, j+32 sums c=32..63
// (half the load depth + fma chain); combined via one shfl_xor(32). Still exact
// f64 over exact f32 products (deterministic; 1e-15-level order change only).
__global__ __launch_bounds__(256) void resc_kernel(const float* __restrict__ xT, const double* __restrict__ xx,
                                                   const int* __restrict__ top32, int* __restrict__ idxOut) {
    int tid = threadIdx.x, lane = tid & 63, w = tid >> 6;
    int grow = blockIdx.x * 4 + w;               // global row 0..B*N-1
    int b = grow >> 12, n = grow & (NNN - 1);
    const float* xTb = xT + (size_t)b * NNN * 64;
    const double* xxb = xx + (size_t)b * NNN;
    int cand = top32[(size_t)grow * 32 + (lane & 31)];
    int ch = (lane >> 5) * 32;                   // c-half base: 0 or 32
    const float* rp = xTb + (size_t)n * 64 + ch;
    const float* cp = xTb + (size_t)cand * 64 + ch;
    double a0 = 0.0, a1 = 0.0, a2 = 0.0, a3 = 0.0;
    #pragma unroll
    for (int c = 0; c < 32; c += 4) {
        float4 rv = *(const float4*)(rp + c);
        float4 cv = *(const float4*)(cp + c);
        a0 = fma((double)rv.x, (double)cv.x, a0);
        a1 = fma((double)rv.y, (double)cv.y, a1);
        a2 = fma((double)rv.z, (double)cv.z, a2);
        a3 = fma((double)rv.w, (double)cv.w, a3);
    }
    double part = (a0 + a1) + (a2 + a3);
    double dsum = part + __shfl_xor(part, 32);
    double d = 2.0 * dsum - xxb[n] - xxb[cand];
    unsigned long long key = (lane < 32) ? packkey(d, cand) : 0ULL;
    unsigned long long S = (lane < KK) ? 0ULL : ~0ULL;
    unsigned long long T = 0;
    unsigned long long m = __ballot(key > T);
    while (m) {
        int src = (int)__builtin_ctzll(m); m &= m - 1;
        unsigned long long kb = __shfl(key, src);
        if (kb > T) {
            unsigned long long u = __shfl_down(S, 1);
            unsigned long long mx = (S < kb) ? kb : S;
            S = (u < kb) ? u : mx;
            T = __shfl(S, 0);
        }
    }
    if (lane < KK)                              // ascending lanes -> descending out
        idxOut[(size_t)grow * KK + (KK - 1 - lane)] = 4095 - (int)(S & 0xFFFULL);
}

// ---------------- K4: 16 points/block (4/CU), h1/h2/max fused (UNCHANGED) ----------------
__global__ __launch_bounds__(256) void edge_kernel(const float* __restrict__ A, const float* __restrict__ Bv,
        const int* __restrict__ idx, const float* __restrict__ w2,
        const float* __restrict__ g1, const float* __restrict__ be1, const float* __restrict__ m1, const float* __restrict__ v1,
        const float* __restrict__ g2, const float* __restrict__ be2, const float* __restrict__ m2, const float* __restrict__ v2,
        float* __restrict__ out) {
    __shared__ float h1buf[4][KK][64];
    __shared__ float resT[64][17];
    int tid = threadIdx.x;
    int lane = tid & 63, w = tid >> 6;
    int b = blockIdx.x >> 8;
    int n0 = (blockIdx.x & 255) * 16;
    float s1 = g1[lane] * rsqrtf(v1[lane] + EPSF);
    float bb1 = be1[lane] - m1[lane] * s1;
    float s2 = g2[lane] * rsqrtf(v2[lane] + EPSF);
    float bb2 = be2[lane] - m2[lane] * s2;
    float w2r[64];
    #pragma unroll
    for (int o = 0; o < 64; ++o) w2r[o] = w2[lane * 64 + o];
    for (int p = 0; p < 4; ++p) {
        int n = n0 + w * 4 + p;
        size_t pb = (size_t)b * NNN + n;
        float bv = Bv[pb * 64 + lane];
        const int* ip = idx + pb * KK;
        #pragma unroll
        for (int k = 0; k < KK; ++k) {
            int nb = ip[k];
            float av = A[((size_t)b * NNN + nb) * 64 + lane];
            h1buf[w][k][lane] = fmaxf(0.f, fmaf(av + bv, s1, bb1));
        }
        __syncthreads();
        float mx = -1e30f;
        for (int k = 0; k < KK; ++k) {
            const float4* hb = (const float4*)&h1buf[w][k][0];
            float dot = 0.f;
            #pragma unroll
            for (int o4 = 0; o4 < 16; ++o4) {
                float4 h = hb[o4];
                dot = fmaf(w2r[o4 * 4 + 0], h.x, dot);
                dot = fmaf(w2r[o4 * 4 + 1], h.y, dot);
                dot = fmaf(w2r[o4 * 4 + 2], h.z, dot);
                dot = fmaf(w2r[o4 * 4 + 3], h.w, dot);
            }
            mx = fmaxf(mx, fmaxf(0.f, fmaf(dot, s2, bb2)));
        }
        resT[lane][w * 4 + p] = mx;
        __syncthreads();
    }
    for (int i = tid; i < 64 * 16; i += 256) {
        int o2 = i >> 4, pp = i & 15;
        out[((size_t)b * 64 + o2) * NNN + n0 + pp] = resT[o2][pp];
    }
}

extern "C" void kernel_launch(void* const* d_in, const int* in_sizes, int n_in,
                              void* d_out, int out_size, void* d_ws, size_t ws_size,
                              hipStream_t stream) {
    const float* x   = (const float*)d_in[0];
    const float* w1  = (const float*)d_in[1];
    const float* g1  = (const float*)d_in[2];
    const float* be1 = (const float*)d_in[3];
    const float* m1  = (const float*)d_in[4];
    const float* v1  = (const float*)d_in[5];
    const float* w2  = (const float*)d_in[6];
    const float* g2  = (const float*)d_in[7];
    const float* be2 = (const float*)d_in[8];
    const float* m2  = (const float*)d_in[9];
    const float* v2  = (const float*)d_in[10];
    // ws: xx 128KB | A 4MB | Bv 4MB | idx20 1.31MB | top32 2MB | xT 4MB | xbf1 2MB | xbf2 2MB
    char* ws = (char*)d_ws;
    double* xx   = (double*)ws;
    float*  A    = (float*)(ws + 131072);
    float*  Bv   = (float*)(ws + 131072 + 4194304);
    int*    nidx = (int*)(ws + 131072 + 2 * 4194304);
    int*    t32  = (int*)(ws + 131072 + 2 * 4194304 + 1310720);
    float*  xT   = (float*)(ws + 131072 + 2 * 4194304 + 1310720 + 2097152);
    short*  xbf1 = (short*)(ws + 131072 + 3 * 4194304 + 1310720 + 2097152);
    short*  xbf2 = (short*)(ws + 131072 + 3 * 4194304 + 1310720 + 2 * 2097152);
    float*  out  = (float*)d_out;

    hipLaunchKernelGGL(pack_kernel, dim3(BB * 64), dim3(256), 0, stream, x, xT, xbf1, xbf2, xx);
    hipLaunchKernelGGL(proj_kernel, dim3(BB * (NNN / 64)), dim3(256), 0, stream, x, w1, A, Bv);
    hipLaunchKernelGGL(scr_kernel,  dim3(BB * (NNN / 16)), dim3(256), 0, stream, xbf1, xbf2, xx, t32);
    hipLaunchKernelGGL(resc_kernel, dim3(BB * NNN / 4), dim3(256), 0, stream, xT, xx, t32, nidx);
    hipLaunchKernelGGL(edge_kernel, dim3(BB * (NNN / 16)), dim3(256), 0, stream,
                       A, Bv, nidx, w2, g1, be1, m1, v1, g2, be2, m2, v2, out);
}

// Round 21
// 326.198 us; speedup vs baseline: 1.0914x; 1.0131x over previous
//
#include <hip/hip_runtime.h>

#define BB 4
#define CC 64
#define NNN 4096
#define OO 64
#define KK 20
#define EPSF 1e-5f

typedef __attribute__((ext_vector_type(8))) short bf8;
typedef __attribute__((ext_vector_type(4))) float f32x4;

// ---------------- helpers ----------------
__device__ __forceinline__ short f2bf(float f) {          // RNE f32->bf16
    unsigned u = __float_as_uint(f);
    unsigned r = (u + 0x7fffu + ((u >> 16) & 1u)) >> 16;
    return (short)r;
}
__device__ __forceinline__ float bf2f(short s) {
    return __uint_as_float(((unsigned)(unsigned short)s) << 16);
}
__device__ __forceinline__ unsigned long long packkey(double d, int j) {
    unsigned long long u = __double_as_longlong(d);
    u ^= (unsigned long long)((long long)u >> 63) | 0x8000000000000000ULL;
    return (u & ~0xFFFULL) | (unsigned long long)(4095 - j);
}

// ---------------- K1: pack x into point-major f32 + bf16 hi/lo splits, fused xx ----------------
__global__ __launch_bounds__(256) void pack_kernel(const float* __restrict__ x, float* __restrict__ xT,
                                                   short* __restrict__ xbf1, short* __restrict__ xbf2,
                                                   double* __restrict__ xx) {
    __shared__ float tile[64][65];
    int tid = threadIdx.x;
    int b = blockIdx.x >> 6;                     // 64 chunks per batch
    int n0 = (blockIdx.x & 63) * 64;
    const float* xb = x + (size_t)b * CC * NNN;
    for (int i = tid; i < 64 * 16; i += 256) {   // 64 c-rows x 16 float4
        int c = i >> 4, q = i & 15;
        *(float4*)&tile[c][q * 4] = *(const float4*)(xb + (size_t)c * NNN + n0 + q * 4);
    }
    __syncthreads();
    if (tid < 64) {                              // fused xx (ascending c, f64)
        double s = 0.0;
        for (int c = 0; c < CC; ++c) {
            double v = (double)tile[c][tid];
            s += v * v;
        }
        xx[(size_t)b * NNN + n0 + tid] = s;
    }
    size_t obase = ((size_t)b * NNN + n0) * 64;
    for (int i = tid; i < 64 * 64; i += 256) {
        int nl = i >> 6, c = i & 63;
        float v = tile[c][nl];
        size_t o = obase + (size_t)nl * 64 + c;
        xT[o] = v;
        short h = f2bf(v);
        xbf1[o] = h;
        xbf2[o] = f2bf(v - bf2f(h));
    }
}

// ---------------- K2: per-point projections A = x*w1a^T, Bv = x*(w1b-w1a)^T ----------------
__global__ __launch_bounds__(256) void proj_kernel(const float* __restrict__ x, const float* __restrict__ w1,
                                                   float* __restrict__ A, float* __restrict__ Bv) {
    __shared__ float xs[CC][64];       // [c][p]
    __shared__ float ws1[OO][129];     // padded
    int tid = threadIdx.x;
    int b = blockIdx.x >> 6;
    int p0 = (blockIdx.x & 63) << 6;
    const float* xb = x + (size_t)b * CC * NNN;
    for (int i = tid; i < CC * 16; i += 256) {
        int c = i >> 4, q = i & 15;
        *(float4*)&xs[c][q * 4] = *(const float4*)(xb + (size_t)c * NNN + p0 + q * 4);
    }
    for (int i = tid; i < OO * 32; i += 256) {
        int o = i >> 5, q = i & 31;
        float4 v = *(const float4*)(w1 + o * 128 + q * 4);
        ws1[o][q * 4 + 0] = v.x; ws1[o][q * 4 + 1] = v.y;
        ws1[o][q * 4 + 2] = v.z; ws1[o][q * 4 + 3] = v.w;
    }
    __syncthreads();
    int ti = tid >> 4, tj = tid & 15;
    float aA[4][4] = {{0.f}}, aD[4][4] = {{0.f}};
    for (int c = 0; c < CC; ++c) {
        float4 xv4 = *(const float4*)&xs[c][ti * 4];
        float xv[4] = {xv4.x, xv4.y, xv4.z, xv4.w};
        #pragma unroll
        for (int oo = 0; oo < 4; ++oo) {
            float wa = ws1[tj * 4 + oo][c];
            float wd = ws1[tj * 4 + oo][64 + c] - wa;
            #pragma unroll
            for (int pp = 0; pp < 4; ++pp) {
                aA[pp][oo] = fmaf(xv[pp], wa, aA[pp][oo]);
                aD[pp][oo] = fmaf(xv[pp], wd, aD[pp][oo]);
            }
        }
    }
    size_t base = ((size_t)b * NNN + p0) * 64;
    #pragma unroll
    for (int pp = 0; pp < 4; ++pp) {
        int p = ti * 4 + pp;
        *(float4*)(A  + base + (size_t)p * 64 + tj * 4) = make_float4(aA[pp][0], aA[pp][1], aA[pp][2], aA[pp][3]);
        *(float4*)(Bv + base + (size_t)p * 64 + tj * 4) = make_float4(aD[pp][0], aD[pp][1], aD[pp][2], aD[pp][3]);
    }
}

// ---------------- K3: bf16 MFMA screen -> top-32 -> FUSED exact-f64 rescore -> top-20 ----------------
// r19/r20 screen verbatim. New tail: each wave rescores its 4 rows' top-32 straight
// from registers (r20 resc math verbatim: split-c f64, shfl_xor(32), u64 packkey,
// 20-deep ballot-insert, descending write). Deletes resc kernel + top32 buffer.
__global__ __launch_bounds__(256, 4) void scr_kernel(const short* __restrict__ xbf1, const short* __restrict__ xbf2,
                                                     const float* __restrict__ xT, const double* __restrict__ xx,
                                                     int* __restrict__ idxOut) {
    __shared__ unsigned dK[2][16][260];             // 33280 B -> 4 blocks/CU
    int tid = threadIdx.x, lane = tid & 63, w = tid >> 6;   // 4 waves
    int b = blockIdx.x >> 8, r0 = (blockIdx.x & 255) * 16;
    const short* x1b = xbf1 + (size_t)b * NNN * 64;
    const short* x2b = xbf2 + (size_t)b * NNN * 64;
    const double* xxb = xx + (size_t)b * NNN;
    int lr = lane & 15, lk = lane >> 4;
    double xr0 = xxb[r0 + 4 * lk + 0], xr1 = xxb[r0 + 4 * lk + 1],
           xr2 = xxb[r0 + 4 * lk + 2], xr3 = xxb[r0 + 4 * lk + 3];

    size_t abase = (size_t)(r0 + lr) * 64 + lk * 8;
    bf8 A1k0 = *(const bf8*)(x1b + abase);
    bf8 A2k0 = *(const bf8*)(x2b + abase);
    bf8 A1k1 = *(const bf8*)(x1b + abase + 32);
    bf8 A2k1 = *(const bf8*)(x2b + abase + 32);

    unsigned S0, S1, S2, S3;
    S0 = S1 = S2 = S3 = (lane < 32) ? 0u : 0xFFFFFFFFu;
    unsigned T0 = 0, T1 = 0, T2 = 0, T3 = 0;

    #define PROC(RL, KEY) { \
        unsigned long long m = __ballot((KEY) > T##RL); \
        while (m) { \
            int src = (int)__builtin_ctzll(m); m &= m - 1; \
            unsigned kb = (unsigned)__builtin_amdgcn_readlane((int)(KEY), src); \
            if (kb > T##RL) { \
                unsigned u = __shfl_down(S##RL, 1); \
                unsigned mx = (S##RL < kb) ? kb : S##RL; \
                S##RL = (u < kb) ? u : mx; \
                T##RL = (unsigned)__builtin_amdgcn_readfirstlane((int)S##RL); \
            } \
        } \
    }
    #define SELROW(RL, CUR) { \
        unsigned k0_ = dK[CUR][w * 4 + RL][0 * 64 + lane]; \
        unsigned k1_ = dK[CUR][w * 4 + RL][1 * 64 + lane]; \
        unsigned k2_ = dK[CUR][w * 4 + RL][2 * 64 + lane]; \
        unsigned k3_ = dK[CUR][w * 4 + RL][3 * 64 + lane]; \
        PROC(RL, k0_) PROC(RL, k1_) PROC(RL, k2_) PROC(RL, k3_) \
    }
    #define SELALL(CUR) SELROW(0, CUR) SELROW(1, CUR) SELROW(2, CUR) SELROW(3, CUR)

    #define CHAIN(ACC, CB) { \
        size_t bb_ = (size_t)((CB) + lr) * 64 + lk * 8; \
        bf8 B1k0 = *(const bf8*)(x1b + bb_); \
        bf8 B2k0 = *(const bf8*)(x2b + bb_); \
        bf8 B1k1 = *(const bf8*)(x1b + bb_ + 32); \
        bf8 B2k1 = *(const bf8*)(x2b + bb_ + 32); \
        ACC = __builtin_amdgcn_mfma_f32_16x16x32_bf16(A1k0, B1k0, ACC, 0, 0, 0); \
        ACC = __builtin_amdgcn_mfma_f32_16x16x32_bf16(A1k1, B1k1, ACC, 0, 0, 0); \
        ACC = __builtin_amdgcn_mfma_f32_16x16x32_bf16(A1k0, B2k0, ACC, 0, 0, 0); \
        ACC = __builtin_amdgcn_mfma_f32_16x16x32_bf16(A1k1, B2k1, ACC, 0, 0, 0); \
        ACC = __builtin_amdgcn_mfma_f32_16x16x32_bf16(A2k0, B1k0, ACC, 0, 0, 0); \
        ACC = __builtin_amdgcn_mfma_f32_16x16x32_bf16(A2k1, B1k1, ACC, 0, 0, 0); \
    }

    for (int t = 0; t < 16; ++t) {
        int j0 = t * 256, cur = t & 1;
        f32x4 acc0 = {0.f, 0.f, 0.f, 0.f}, acc1 = {0.f, 0.f, 0.f, 0.f};
        f32x4 acc2 = {0.f, 0.f, 0.f, 0.f}, acc3 = {0.f, 0.f, 0.f, 0.f};
        CHAIN(acc0, j0 + w * 64 + 0)
        CHAIN(acc1, j0 + w * 64 + 16)
        CHAIN(acc2, j0 + w * 64 + 32)
        CHAIN(acc3, j0 + w * 64 + 48)
        #define EPI(Q, R) { \
            int col = w * 64 + (Q) * 16 + lr; \
            float df = (float)(2.0 * (double)acc##Q[R] - xr##R - xxb[j0 + col]); \
            unsigned u = __float_as_uint(df); \
            u ^= (unsigned)((int)u >> 31) | 0x80000000u; \
            dK[cur][4 * lk + R][col] = (u & 0xFFFFF000u) | (unsigned)(4095 - (j0 + col)); \
        }
        EPI(0,0) EPI(0,1) EPI(0,2) EPI(0,3)
        EPI(1,0) EPI(1,1) EPI(1,2) EPI(1,3)
        EPI(2,0) EPI(2,1) EPI(2,2) EPI(2,3)
        EPI(3,0) EPI(3,1) EPI(3,2) EPI(3,3)
        #undef EPI
        __syncthreads();               // ONE barrier: dK[cur] ready; buffer cur^1 free
        SELALL(cur);
    }
    #undef SELALL
    #undef SELROW
    #undef PROC
    #undef CHAIN

    // ---- fused exact-f64 rescore (r20 resc math verbatim, candidates from regs) ----
    const float* xTb = xT + (size_t)b * NNN * 64;
    int ch = (lane >> 5) * 32;                   // c-half base: 0 or 32
    #define RESC(RL) { \
        int cand = 4095 - (int)(__shfl(S##RL, lane & 31) & 0xFFFu); \
        int rown = r0 + w * 4 + RL; \
        const float* rp = xTb + (size_t)rown * 64 + ch; \
        const float* cp = xTb + (size_t)cand * 64 + ch; \
        double a0 = 0.0, a1 = 0.0, a2 = 0.0, a3 = 0.0; \
        _Pragma("unroll") \
        for (int c = 0; c < 32; c += 4) { \
            float4 rv = *(const float4*)(rp + c); \
            float4 cv = *(const float4*)(cp + c); \
            a0 = fma((double)rv.x, (double)cv.x, a0); \
            a1 = fma((double)rv.y, (double)cv.y, a1); \
            a2 = fma((double)rv.z, (double)cv.z, a2); \
            a3 = fma((double)rv.w, (double)cv.w, a3); \
        } \
        double part = (a0 + a1) + (a2 + a3); \
        double dsum = part + __shfl_xor(part, 32); \
        double dd = 2.0 * dsum - xxb[rown] - xxb[cand]; \
        unsigned long long key = (lane < 32) ? packkey(dd, cand) : 0ULL; \
        unsigned long long SS = (lane < KK) ? 0ULL : ~0ULL; \
        unsigned long long TT = 0; \
        unsigned long long m = __ballot(key > TT); \
        while (m) { \
            int src = (int)__builtin_ctzll(m); m &= m - 1; \
            unsigned long long kb = __shfl(key, src); \
            if (kb > TT) { \
                unsigned long long u = __shfl_down(SS, 1); \
                unsigned long long mx = (SS < kb) ? kb : SS; \
                SS = (u < kb) ? u : mx; \
                TT = __shfl(SS, 0); \
            } \
        } \
        if (lane < KK) \
            idxOut[((size_t)b * NNN + rown) * KK + (KK - 1 - lane)] = 4095 - (int)(SS & 0xFFFULL); \
    }
    RESC(0) RESC(1) RESC(2) RESC(3)
    #undef RESC
}

// ---------------- K4: 16 points/block (4/CU), h1/h2/max fused (UNCHANGED) ----------------
__global__ __launch_bounds__(256) void edge_kernel(const float* __restrict__ A, const float* __restrict__ Bv,
        const int* __restrict__ idx, const float* __restrict__ w2,
        const float* __restrict__ g1, const float* __restrict__ be1, const float* __restrict__ m1, const float* __restrict__ v1,
        const float* __restrict__ g2, const float* __restrict__ be2, const float* __restrict__ m2, const float* __restrict__ v2,
        float* __restrict__ out) {
    __shared__ float h1buf[4][KK][64];
    __shared__ float resT[64][17];
    int tid = threadIdx.x;
    int lane = tid & 63, w = tid >> 6;
    int b = blockIdx.x >> 8;
    int n0 = (blockIdx.x & 255) * 16;
    float s1 = g1[lane] * rsqrtf(v1[lane] + EPSF);
    float bb1 = be1[lane] - m1[lane] * s1;
    float s2 = g2[lane] * rsqrtf(v2[lane] + EPSF);
    float bb2 = be2[lane] - m2[lane] * s2;
    float w2r[64];
    #pragma unroll
    for (int o = 0; o < 64; ++o) w2r[o] = w2[lane * 64 + o];
    for (int p = 0; p < 4; ++p) {
        int n = n0 + w * 4 + p;
        size_t pb = (size_t)b * NNN + n;
        float bv = Bv[pb * 64 + lane];
        const int* ip = idx + pb * KK;
        #pragma unroll
        for (int k = 0; k < KK; ++k) {
            int nb = ip[k];
            float av = A[((size_t)b * NNN + nb) * 64 + lane];
            h1buf[w][k][lane] = fmaxf(0.f, fmaf(av + bv, s1, bb1));
        }
        __syncthreads();
        float mx = -1e30f;
        for (int k = 0; k < KK; ++k) {
            const float4* hb = (const float4*)&h1buf[w][k][0];
            float dot = 0.f;
            #pragma unroll
            for (int o4 = 0; o4 < 16; ++o4) {
                float4 h = hb[o4];
                dot = fmaf(w2r[o4 * 4 + 0], h.x, dot);
                dot = fmaf(w2r[o4 * 4 + 1], h.y, dot);
                dot = fmaf(w2r[o4 * 4 + 2], h.z, dot);
                dot = fmaf(w2r[o4 * 4 + 3], h.w, dot);
            }
            mx = fmaxf(mx, fmaxf(0.f, fmaf(dot, s2, bb2)));
        }
        resT[lane][w * 4 + p] = mx;
        __syncthreads();
    }
    for (int i = tid; i < 64 * 16; i += 256) {
        int o2 = i >> 4, pp = i & 15;
        out[((size_t)b * 64 + o2) * NNN + n0 + pp] = resT[o2][pp];
    }
}

extern "C" void kernel_launch(void* const* d_in, const int* in_sizes, int n_in,
                              void* d_out, int out_size, void* d_ws, size_t ws_size,
                              hipStream_t stream) {
    const float* x   = (const float*)d_in[0];
    const float* w1  = (const float*)d_in[1];
    const float* g1  = (const float*)d_in[2];
    const float* be1 = (const float*)d_in[3];
    const float* m1  = (const float*)d_in[4];
    const float* v1  = (const float*)d_in[5];
    const float* w2  = (const float*)d_in[6];
    const float* g2  = (const float*)d_in[7];
    const float* be2 = (const float*)d_in[8];
    const float* m2  = (const float*)d_in[9];
    const float* v2  = (const float*)d_in[10];
    // ws: xx 128KB | A 4MB | Bv 4MB | idx20 1.31MB | xT 4MB | xbf1 2MB | xbf2 2MB
    char* ws = (char*)d_ws;
    double* xx   = (double*)ws;
    float*  A    = (float*)(ws + 131072);
    float*  Bv   = (float*)(ws + 131072 + 4194304);
    int*    nidx = (int*)(ws + 131072 + 2 * 4194304);
    float*  xT   = (float*)(ws + 131072 + 2 * 4194304 + 1310720);
    short*  xbf1 = (short*)(ws + 131072 + 3 * 4194304 + 1310720);
    short*  xbf2 = (short*)(ws + 131072 + 3 * 4194304 + 1310720 + 2097152);
    float*  out  = (float*)d_out;

    hipLaunchKernelGGL(pack_kernel, dim3(BB * 64), dim3(256), 0, stream, x, xT, xbf1, xbf2, xx);
    hipLaunchKernelGGL(proj_kernel, dim3(BB * (NNN / 64)), dim3(256), 0, stream, x, w1, A, Bv);
    hipLaunchKernelGGL(scr_kernel,  dim3(BB * (NNN / 16)), dim3(256), 0, stream, xbf1, xbf2, xT, xx, nidx);
    hipLaunchKernelGGL(edge_kernel, dim3(BB * (NNN / 16)), dim3(256), 0, stream,
                       A, Bv, nidx, w2, g1, be1, m1, v1, g2, be2, m2, v2, out);
}